// Round 2
// baseline (337.096 us; speedup 1.0000x reference)
//
#include <hip/hip_runtime.h>
#include <hip/hip_bf16.h>

typedef __attribute__((ext_vector_type(4))) float f32x4;
typedef __attribute__((ext_vector_type(8))) short s16x8;
typedef unsigned short u16;
typedef unsigned int u32;

#define DEV __device__ __forceinline__

DEV u16 f2bf(float f) {
  union { float f; u32 u; } v; v.f = f;
  u32 r = v.u + 0x7fffu + ((v.u >> 16) & 1u);
  return (u16)(r >> 16);
}

#define MFMA16(a, b, c) __builtin_amdgcn_mfma_f32_16x16x32_bf16((a), (b), (c), 0, 0, 0)
#define GLD16(g, l) __builtin_amdgcn_global_load_lds((const __attribute__((address_space(1))) u32*)(g), (__attribute__((address_space(3))) u32*)(l), 16, 0, 0)

// ---------------------------------------------------------------------------
// Transpose-cast: src fp32 [768][ncols] -> dst bf16 [ncols][768], with scale.
// grid = 24 * (ncols/32), block 256.
__global__ __launch_bounds__(256) void wcvt_k(const float* __restrict__ src,
                                              u16* __restrict__ dst,
                                              int ncols, float scale) {
  __shared__ float tb[32][33];
  int tile = blockIdx.x;
  int tk = (tile % 24) * 32;
  int tn = (tile / 24) * 32;
  int tx = threadIdx.x & 31, ty = threadIdx.x >> 5;
#pragma unroll
  for (int i = 0; i < 4; i++)
    tb[ty + i * 8][tx] = src[(size_t)(tk + ty + i * 8) * ncols + tn + tx];
  __syncthreads();
#pragma unroll
  for (int i = 0; i < 4; i++)
    dst[(size_t)(tn + ty + i * 8) * 768 + tk + tx] = f2bf(tb[tx][ty + i * 8] * scale);
}

// ---------------------------------------------------------------------------
// Patch embed (8x8 conv, stride 8) + LayerNorm + pos  ->  x0 fp32 + x0 bf16.
// grid = 1024 (4 tokens per block), block 256.
__global__ __launch_bounds__(256) void patch_ln(
    const float* __restrict__ sam, const float* __restrict__ cw,
    const float* __restrict__ cb, const float* __restrict__ g,
    const float* __restrict__ bb, const float* __restrict__ pos,
    float* __restrict__ x0f, u16* __restrict__ x0b) {
  int blk = blockIdx.x;
  int b = blk >> 8, nq = blk & 255;  // tokens nq*4 .. nq*4+3
  int t = threadIdx.x;
  __shared__ float pix[4][64];
  {
    int tk = t >> 6, p = t & 63;
    int n = nq * 4 + tk;
    int gi = n >> 5, gj = n & 31;
    pix[tk][p] = sam[b * 65536 + (gi * 8 + (p >> 3)) * 256 + gj * 8 + (p & 7)];
  }
  __syncthreads();
  float acc[3][4];
#pragma unroll
  for (int u = 0; u < 3; u++) {
    int d = t + u * 256;
    const float4* w4 = (const float4*)(cw + (size_t)d * 64);
    float a0 = cb[d];
    float av0 = a0, av1 = a0, av2 = a0, av3 = a0;
#pragma unroll
    for (int pc = 0; pc < 16; pc++) {
      float4 w = w4[pc];
      av0 += w.x * pix[0][pc * 4] + w.y * pix[0][pc * 4 + 1] + w.z * pix[0][pc * 4 + 2] + w.w * pix[0][pc * 4 + 3];
      av1 += w.x * pix[1][pc * 4] + w.y * pix[1][pc * 4 + 1] + w.z * pix[1][pc * 4 + 2] + w.w * pix[1][pc * 4 + 3];
      av2 += w.x * pix[2][pc * 4] + w.y * pix[2][pc * 4 + 1] + w.z * pix[2][pc * 4 + 2] + w.w * pix[2][pc * 4 + 3];
      av3 += w.x * pix[3][pc * 4] + w.y * pix[3][pc * 4 + 1] + w.z * pix[3][pc * 4 + 2] + w.w * pix[3][pc * 4 + 3];
    }
    acc[u][0] = av0; acc[u][1] = av1; acc[u][2] = av2; acc[u][3] = av3;
  }
  // per-token mean/var over 768
  float s1[4], s2[4];
#pragma unroll
  for (int tk = 0; tk < 4; tk++) {
    s1[tk] = acc[0][tk] + acc[1][tk] + acc[2][tk];
    s2[tk] = acc[0][tk] * acc[0][tk] + acc[1][tk] * acc[1][tk] + acc[2][tk] * acc[2][tk];
  }
#pragma unroll
  for (int m = 1; m < 64; m <<= 1) {
#pragma unroll
    for (int tk = 0; tk < 4; tk++) {
      s1[tk] += __shfl_xor(s1[tk], m);
      s2[tk] += __shfl_xor(s2[tk], m);
    }
  }
  __shared__ float red[2][4][4];
  int wid = t >> 6;
  if ((t & 63) == 0) {
#pragma unroll
    for (int tk = 0; tk < 4; tk++) { red[0][wid][tk] = s1[tk]; red[1][wid][tk] = s2[tk]; }
  }
  __syncthreads();
  float mu[4], rs[4];
#pragma unroll
  for (int tk = 0; tk < 4; tk++) {
    float S1 = red[0][0][tk] + red[0][1][tk] + red[0][2][tk] + red[0][3][tk];
    float S2 = red[1][0][tk] + red[1][1][tk] + red[1][2][tk] + red[1][3][tk];
    mu[tk] = S1 * (1.0f / 768.0f);
    float var = S2 * (1.0f / 768.0f) - mu[tk] * mu[tk];
    rs[tk] = rsqrtf(var + 1e-5f);
  }
#pragma unroll
  for (int u = 0; u < 3; u++) {
    int d = t + u * 256;
    float gg = g[d], bbv = bb[d];
#pragma unroll
    for (int tk = 0; tk < 4; tk++) {
      int n = nq * 4 + tk;
      float val = (acc[u][tk] - mu[tk]) * rs[tk] * gg + bbv + pos[(size_t)n * 768 + d];
      size_t idx = ((size_t)(b * 1024 + n)) * 768 + d;
      x0f[idx] = val;
      x0b[idx] = f2bf(val);
    }
  }
}

// ---------------------------------------------------------------------------
// 128x128 bf16 MFMA GEMM, BK=32, 4 waves. A [M][K], BT [N][K] (B transposed).
// EPI 0: qkv scatter epilogue.  EPI 1: proj + bias + residual -> fp32 out.
template <int EPI>
__global__ __launch_bounds__(256, 2) void gemm128(
    const u16* __restrict__ A, const u16* __restrict__ BT, int M, int N, int K,
    u16* __restrict__ q, u16* __restrict__ kk_, u16* __restrict__ vt,
    const float* __restrict__ pb, const float* __restrict__ x0f,
    float* __restrict__ outp) {
  __shared__ __align__(16) u16 Al[128 * 32];
  __shared__ __align__(16) u16 Bl[128 * 32];
  int m0 = blockIdx.y * 128, n0 = blockIdx.x * 128;
  int tid = threadIdx.x, lane = tid & 63, wid = tid >> 6;
  int wr = wid >> 1, wc = wid & 1;
  f32x4 acc[4][4] = {};
  int arow = lane >> 2, acol = (lane & 3) * 8;
  const u16* ag = A + (size_t)(m0 + wid * 32 + arow) * K + acol;
  const u16* bg = BT + (size_t)(n0 + wid * 32 + arow) * K + acol;
  u16* alp = Al + wid * 32 * 32;
  u16* blp = Bl + wid * 32 * 32;
  for (int kt = 0; kt < K; kt += 32) {
    GLD16(ag + kt, alp);
    GLD16(ag + kt + 16 * K, alp + 16 * 32);
    GLD16(bg + kt, blp);
    GLD16(bg + kt + 16 * K, blp + 16 * 32);
    __syncthreads();
    s16x8 af[4], bf[4];
#pragma unroll
    for (int m = 0; m < 4; m++)
      af[m] = *(const s16x8*)&Al[(wr * 64 + m * 16 + (lane & 15)) * 32 + (lane >> 4) * 8];
#pragma unroll
    for (int nn = 0; nn < 4; nn++)
      bf[nn] = *(const s16x8*)&Bl[(wc * 64 + nn * 16 + (lane & 15)) * 32 + (lane >> 4) * 8];
#pragma unroll
    for (int m = 0; m < 4; m++)
#pragma unroll
      for (int nn = 0; nn < 4; nn++)
        acc[m][nn] = MFMA16(af[m], bf[nn], acc[m][nn]);
    __syncthreads();
  }
#pragma unroll
  for (int m = 0; m < 4; m++) {
    int rbase = m0 + wr * 64 + m * 16 + ((lane >> 4) << 2);
#pragma unroll
    for (int nn = 0; nn < 4; nn++) {
      int col = n0 + wc * 64 + nn * 16 + (lane & 15);
      f32x4 v = acc[m][nn];
      if (EPI == 0) {
        if (col < 1536) {
          int cc = (col < 768) ? col : col - 768;
          int h = cc / 96, hd = cc % 96;
          u16* dst = (col < 768) ? q : kk_;
          int bq = (rbase >> 10) * 8 + h;
#pragma unroll
          for (int i = 0; i < 4; i++) {
            int row = rbase + i;
            dst[((size_t)bq * 1024 + (row & 1023)) * 96 + hd] = f2bf(v[i]);
          }
        } else {
          int cc = col - 1536;
          int h = cc / 96, hd = cc % 96;
          int bq = (rbase >> 10) * 8 + h;
          ushort4 pk;
          pk.x = f2bf(v[0]); pk.y = f2bf(v[1]); pk.z = f2bf(v[2]); pk.w = f2bf(v[3]);
          *(ushort4*)&vt[((size_t)bq * 96 + hd) * 1024 + (rbase & 1023)] = pk;
        }
      } else {
        float add = pb[col];
#pragma unroll
        for (int i = 0; i < 4; i++) {
          size_t idx = (size_t)(rbase + i) * 768 + col;
          outp[idx] = v[i] + add + x0f[idx];
        }
      }
    }
  }
}

// ---------------------------------------------------------------------------
// Flash attention. grid = 256 (32 bh * 8 q-blocks of 128), 4 waves * 32 q-rows.
// q,k: [bh][n][96] bf16 (q pre-scaled). vt: [bh][96][n] bf16. o: [b*1024+n][768].
__global__ __launch_bounds__(256, 2) void attn_k(
    const u16* __restrict__ qg, const u16* __restrict__ kg,
    const u16* __restrict__ vg, u16* __restrict__ o) {
  int bh = blockIdx.x >> 3, qb = blockIdx.x & 7;
  int b = bh >> 3, h = bh & 7;
  int tid = threadIdx.x, lane = tid & 63, wid = tid >> 6;
  int q0 = qb * 128 + wid * 32;
  s16x8 aq[2][3];
#pragma unroll
  for (int mf = 0; mf < 2; mf++)
#pragma unroll
    for (int kc = 0; kc < 3; kc++)
      aq[mf][kc] = *(const s16x8*)&qg[((size_t)bh * 1024 + q0 + mf * 16 + (lane & 15)) * 96 + kc * 32 + (lane >> 4) * 8];
  float mrun[2][4], lrun[2][4];
  f32x4 accO[2][6] = {};
#pragma unroll
  for (int mf = 0; mf < 2; mf++)
#pragma unroll
    for (int i = 0; i < 4; i++) { mrun[mf][i] = -1e30f; lrun[mf][i] = 0.0f; }
  __shared__ __align__(16) u16 Kl[64][104];
  __shared__ __align__(16) u16 VTl[96][72];
  __shared__ __align__(16) u16 Pl[4][32][72];
  const u16* kbase = kg + (size_t)bh * 1024 * 96;
  const u16* vbase = vg + (size_t)bh * 96 * 1024;
  int kkey[3], koff[3], vhd[3], vko[3];
#pragma unroll
  for (int it = 0; it < 3; it++) {
    int c = it * 256 + tid;
    kkey[it] = c / 12; koff[it] = (c % 12) * 8;
    vhd[it] = c >> 3;  vko[it] = (c & 7) * 8;
  }
  for (int kt = 0; kt < 16; kt++) {
#pragma unroll
    for (int it = 0; it < 3; it++) {
      *(uint4*)&Kl[kkey[it]][koff[it]] = *(const uint4*)&kbase[(size_t)(kt * 64 + kkey[it]) * 96 + koff[it]];
      *(uint4*)&VTl[vhd[it]][vko[it]] = *(const uint4*)&vbase[(size_t)vhd[it] * 1024 + kt * 64 + vko[it]];
    }
    __syncthreads();
    // S = Q K^T  (per wave: 32 q-rows x 64 keys)
    f32x4 s[2][4] = {};
#pragma unroll
    for (int nf = 0; nf < 4; nf++) {
#pragma unroll
      for (int kc = 0; kc < 3; kc++) {
        s16x8 bk = *(const s16x8*)&Kl[nf * 16 + (lane & 15)][kc * 32 + (lane >> 4) * 8];
        s[0][nf] = MFMA16(aq[0][kc], bk, s[0][nf]);
        s[1][nf] = MFMA16(aq[1][kc], bk, s[1][nf]);
      }
    }
    // online softmax per owned row
#pragma unroll
    for (int mf = 0; mf < 2; mf++) {
#pragma unroll
      for (int i = 0; i < 4; i++) {
        float rm = fmaxf(fmaxf(s[mf][0][i], s[mf][1][i]), fmaxf(s[mf][2][i], s[mf][3][i]));
#pragma unroll
        for (int m = 1; m < 16; m <<= 1) rm = fmaxf(rm, __shfl_xor(rm, m));
        float newm = fmaxf(mrun[mf][i], rm);
        float alpha = __expf(mrun[mf][i] - newm);
        float ps = 0.0f;
#pragma unroll
        for (int nf = 0; nf < 4; nf++) {
          float p = __expf(s[mf][nf][i] - newm);
          s[mf][nf][i] = p;
          ps += p;
        }
#pragma unroll
        for (int m = 1; m < 16; m <<= 1) ps += __shfl_xor(ps, m);
        lrun[mf][i] = lrun[mf][i] * alpha + ps;
        mrun[mf][i] = newm;
#pragma unroll
        for (int nf = 0; nf < 6; nf++) accO[mf][nf][i] *= alpha;
      }
#pragma unroll
      for (int nf = 0; nf < 4; nf++)
#pragma unroll
        for (int i = 0; i < 4; i++)
          Pl[wid][mf * 16 + ((lane >> 4) << 2) + i][nf * 16 + (lane & 15)] = f2bf(s[mf][nf][i]);
    }
    asm volatile("s_waitcnt lgkmcnt(0)" ::: "memory");
    __builtin_amdgcn_sched_barrier(0);
    // O += P V
#pragma unroll
    for (int kc = 0; kc < 2; kc++) {
      s16x8 ap0 = *(const s16x8*)&Pl[wid][0 + (lane & 15)][kc * 32 + (lane >> 4) * 8];
      s16x8 ap1 = *(const s16x8*)&Pl[wid][16 + (lane & 15)][kc * 32 + (lane >> 4) * 8];
#pragma unroll
      for (int nf = 0; nf < 6; nf++) {
        s16x8 bv = *(const s16x8*)&VTl[nf * 16 + (lane & 15)][kc * 32 + (lane >> 4) * 8];
        accO[0][nf] = MFMA16(ap0, bv, accO[0][nf]);
        accO[1][nf] = MFMA16(ap1, bv, accO[1][nf]);
      }
    }
    __syncthreads();
  }
#pragma unroll
  for (int mf = 0; mf < 2; mf++) {
#pragma unroll
    for (int i = 0; i < 4; i++) {
      float inv = 1.0f / lrun[mf][i];
      int tok = qb * 128 + wid * 32 + mf * 16 + ((lane >> 4) << 2) + i;
      u16* orow = o + ((size_t)(b * 1024 + tok)) * 768 + h * 96;
#pragma unroll
      for (int nf = 0; nf < 6; nf++)
        orow[nf * 16 + (lane & 15)] = f2bf(accO[mf][nf][i] * inv);
    }
  }
}

// ---------------------------------------------------------------------------
extern "C" void kernel_launch(void* const* d_in, const int* in_sizes, int n_in,
                              void* d_out, int out_size, void* d_ws, size_t ws_size,
                              hipStream_t stream) {
  const float* sam    = (const float*)d_in[0];
  const float* conv_w = (const float*)d_in[1];
  const float* conv_b = (const float*)d_in[2];
  const float* ln_g   = (const float*)d_in[3];
  const float* ln_b   = (const float*)d_in[4];
  const float* pos    = (const float*)d_in[5];
  const float* q_w    = (const float*)d_in[6] + (size_t)20 * 768 * 768;
  const float* kv_w   = (const float*)d_in[7] + (size_t)20 * 768 * 1536;
  const float* proj_w = (const float*)d_in[8] + (size_t)20 * 768 * 768;
  const float* proj_b = (const float*)d_in[9] + (size_t)20 * 768;

  char* ws = (char*)d_ws;
  float* x0f  = (float*)ws; ws += (size_t)4096 * 768 * 4;
  u16* x0b    = (u16*)ws;   ws += (size_t)4096 * 768 * 2;
  u16* wqkvT  = (u16*)ws;   ws += (size_t)2304 * 768 * 2;
  u16* pwT    = (u16*)ws;   ws += (size_t)768 * 768 * 2;
  u16* qs     = (u16*)ws;   ws += (size_t)32 * 1024 * 96 * 2;
  u16* ks     = (u16*)ws;   ws += (size_t)32 * 1024 * 96 * 2;
  u16* vts    = (u16*)ws;   ws += (size_t)32 * 96 * 1024 * 2;
  u16* ob     = (u16*)ws;   ws += (size_t)4096 * 768 * 2;

  const float SCALE = 0.10206207261596577f;  // 96^-0.5

  wcvt_k<<<24 * 24, 256, 0, stream>>>(q_w, wqkvT, 768, SCALE);
  wcvt_k<<<24 * 48, 256, 0, stream>>>(kv_w, wqkvT + (size_t)768 * 768, 1536, 1.0f);
  wcvt_k<<<24 * 24, 256, 0, stream>>>(proj_w, pwT, 768, 1.0f);
  patch_ln<<<1024, 256, 0, stream>>>(sam, conv_w, conv_b, ln_g, ln_b, pos, x0f, x0b);
  dim3 g1(18, 32);
  gemm128<0><<<g1, 256, 0, stream>>>(x0b, wqkvT, 4096, 2304, 768, qs, ks, vts,
                                     nullptr, nullptr, nullptr);
  attn_k<<<256, 256, 0, stream>>>(qs, ks, vts, ob);
  dim3 g2(6, 32);
  gemm128<1><<<g2, 256, 0, stream>>>(ob, pwT, 4096, 768, 768, nullptr, nullptr,
                                     nullptr, proj_b, x0f, (float*)d_out);
}